// Round 13
// baseline (73.372 us; speedup 1.0000x reference)
//
#include <hip/hip_runtime.h>

#define NBINS  10
#define NCLS   80
#define NSLOTS (NCLS * NBINS)   // 800
#define QSF    10240.0f         // 10*2^10: t = q>>10, q = fixed-point p
#define NBLK   512
#define NTHR   512

// ---------------------------------------------------------------------------
// Kernel 1: per-(class,bin) accumulation — R12 champion core, replicated flush.
//   s_pack[slot] u32 = sum_q (bits 0..22, scale 10240) | cnt<<23 (9 bits)
//   s_acc[slot]  u32 = correct count (rare second atomic)
//   Stage = 2 contiguous float4 (8 elems); 2-deep pipeline.
//   Flush: one packed u64 global atomic per slot into replica (blockIdx & mask):
//     sum(0..35) | cnt<<36 (17b) | acc<<53 (11b)
//   -> same-address contention drops 512 -> 512/nrep.
// ---------------------------------------------------------------------------
__global__ void __launch_bounds__(NTHR)
mce_accum(const float4* __restrict__ probas,
          const int*    __restrict__ labels,
          unsigned long long* __restrict__ g_pack,
          unsigned int rep_mask,
          unsigned int nvec) {
    __shared__ unsigned int s_pack[NSLOTS];
    __shared__ unsigned int s_acc[NSLOTS];
    for (int i = threadIdx.x; i < NSLOTS; i += NTHR) { s_pack[i] = 0u; s_acc[i] = 0u; }
    __syncthreads();

    const unsigned int S = gridDim.x * NTHR * 2u;          // stride in float4s
    unsigned int v0 = (blockIdx.x * NTHR + threadIdx.x) * 2u;

#define LOADS(V, Q0, Q1, LAB)                                             \
    {                                                                     \
        Q0 = probas[(V)];                                                 \
        Q1 = probas[(V) + 1];                                             \
        LAB = labels[(V) / 20u];                                          \
    }

#define PROC(V, Q0, Q1, LAB)                                              \
    {                                                                     \
        unsigned int row = (V) / 20u;          /* magic-mul div */        \
        int cbase  = (int)((V) - row * 20u) * 4;                          \
        int labrel = (LAB) - cbase;                                       \
        int sbase  = cbase * NBINS;                                       \
        float pe[8] = {Q0.x, Q0.y, Q0.z, Q0.w, Q1.x, Q1.y, Q1.z, Q1.w};   \
        unsigned int selq = 0u;                                           \
        _Pragma("unroll")                                                 \
        for (int j = 0; j < 8; ++j) {                                     \
            unsigned int q = (unsigned int)__builtin_fmaf(pe[j], QSF, 0.5f); \
            unsigned int t = min(q >> 10, 9u);                            \
            selq = (j == labrel) ? q : selq;                              \
            atomicAdd(&s_pack[sbase + j * NBINS + (int)t], q + (1u << 23)); \
        }                                                                 \
        if ((unsigned int)labrel < 8u) {                                  \
            unsigned int ts = min(selq >> 10, 9u);                        \
            atomicAdd(&s_acc[sbase + labrel * NBINS + (int)ts], 1u);      \
        }                                                                 \
    }

    {
        float4 a0, a1, b0, b1;
        int labA, labB;
        LOADS(v0, a0, a1, labA)
        for (;;) {
            unsigned int w1 = v0 + S;
            bool h1 = w1 < nvec;
            if (h1) LOADS(w1, b0, b1, labB)
            PROC(v0, a0, a1, labA)
            if (!h1) break;
            unsigned int w2 = w1 + S;
            bool h2 = w2 < nvec;
            if (h2) LOADS(w2, a0, a1, labA)
            PROC(w1, b0, b1, labB)
            if (!h2) break;
            v0 = w2;
        }
    }
#undef LOADS
#undef PROC

    __syncthreads();
    {
        unsigned long long* dst = g_pack + (blockIdx.x & rep_mask) * NSLOTS;
        for (int i = threadIdx.x; i < NSLOTS; i += NTHR) {
            unsigned int pk = s_pack[i];
            unsigned int ac = s_acc[i];
            if (pk | ac) {
                unsigned long long sum = pk & 0x7FFFFFu;
                unsigned long long cnt = pk >> 23;
                atomicAdd(&dst[i], sum | (cnt << 36) | ((unsigned long long)ac << 53));
            }
        }
    }
}

// ---------------------------------------------------------------------------
// Kernel 2: finalize. One block, 1024 threads. Sums nrep replicas (carry-safe
// packed addition), unpacks to LDS, then per-class math + reduce.
// ---------------------------------------------------------------------------
__global__ void __launch_bounds__(1024)
mce_finalize(const unsigned long long* __restrict__ g_pack,
             unsigned int nrep,
             float* __restrict__ out) {
    __shared__ unsigned int s_sumq[NSLOTS];
    __shared__ unsigned int s_cnt[NSLOTS];
    __shared__ unsigned int s_acc[NSLOTS];
    __shared__ double s_ce[128];

    int i = threadIdx.x;
    if (i < NSLOTS) {
        unsigned long long w = 0ull;
        for (unsigned int r = 0; r < nrep; ++r)
            w += g_pack[r * NSLOTS + i];
        s_sumq[i] = (unsigned int)(w & 0xFFFFFFFFFull);
        s_cnt[i]  = (unsigned int)((w >> 36) & 0x1FFFFull);
        s_acc[i]  = (unsigned int)(w >> 53);
    }
    __syncthreads();

    int c = threadIdx.x;
    double ce = 0.0;
    if (c < NCLS) {
        double total = 0.0;
        for (int b = 0; b < NBINS; ++b)
            total += (double)s_cnt[c * NBINS + b];
        for (int b = 0; b < NBINS; ++b) {
            unsigned int n = s_cnt[c * NBINS + b];
            if (n > 0u) {
                double fn   = (double)n;
                double conf = ((double)s_sumq[c * NBINS + b] * (1.0 / 10240.0)) / fn;
                double acc  = (double)s_acc[c * NBINS + b] / fn;
                double d    = conf - acc;
                ce += (fn / total) * d * d;
            }
        }
    }
    if (c < 128) s_ce[c] = ce;
    __syncthreads();
    for (int off = 64; off > 0; off >>= 1) {
        if (c < off) s_ce[c] += s_ce[c + off];
        __syncthreads();
    }
    if (c == 0) out[0] = (float)sqrt(s_ce[0] / (double)NCLS);
}

extern "C" void kernel_launch(void* const* d_in, const int* in_sizes, int n_in,
                              void* d_out, int out_size, void* d_ws, size_t ws_size,
                              hipStream_t stream) {
    const float4* probas = (const float4*)d_in[0];
    const int*    labels = (const int*)d_in[1];

    unsigned int nvec = (unsigned int)(in_sizes[0] / 4);  // 20,000,000

    // replica count: 32 if workspace allows, else degrade gracefully
    unsigned int nrep = 32u;
    while (nrep > 1u && ws_size < (size_t)nrep * NSLOTS * 8u) nrep >>= 1;

    unsigned long long* g_pack = (unsigned long long*)d_ws;
    hipMemsetAsync(d_ws, 0, (size_t)nrep * NSLOTS * 8u, stream);

    mce_accum<<<NBLK, NTHR, 0, stream>>>(probas, labels, g_pack, nrep - 1u, nvec);
    mce_finalize<<<1, 1024, 0, stream>>>(g_pack, nrep, (float*)d_out);
}

// Round 14
// 65.010 us; speedup vs baseline: 1.1286x; 1.1286x over previous
//
#include <hip/hip_runtime.h>

#define NBINS  10
#define NCLS   80
#define NSLOTS (NCLS * NBINS)   // 800
#define QSF    2560.0f          // 10*2^8: t = q>>8, q = fixed-point p
#define NBLK   256
#define NTHR   1024

// ---------------------------------------------------------------------------
// Kernel 1: per-(class,bin) accumulation — R12 champion core, 256x1024 geometry.
//   s_pack[slot] u32 = sum_q (bits 0..21, scale 2560) | cnt<<22 (10 bits)
//   s_acc[slot]  u32 = correct count (rare second atomic)
//   Stage = 2 contiguous float4 (8 elems, one row-segment); 2-deep pipeline.
//   Flush: one packed u64 global atomic: sum(0..35) | cnt<<36 (17b) | acc<<53.
// ---------------------------------------------------------------------------
__global__ void __launch_bounds__(NTHR)
mce_accum(const float4* __restrict__ probas,
          const int*    __restrict__ labels,
          unsigned long long* __restrict__ g_pack,
          unsigned int nvec) {
    __shared__ unsigned int s_pack[NSLOTS];
    __shared__ unsigned int s_acc[NSLOTS];
    for (int i = threadIdx.x; i < NSLOTS; i += NTHR) { s_pack[i] = 0u; s_acc[i] = 0u; }
    __syncthreads();

    const unsigned int S = gridDim.x * NTHR * 2u;          // stride in float4s
    unsigned int v0 = (blockIdx.x * NTHR + threadIdx.x) * 2u;

#define LOADS(V, Q0, Q1, LAB)                                             \
    {                                                                     \
        Q0 = probas[(V)];                                                 \
        Q1 = probas[(V) + 1];                                             \
        LAB = labels[(V) / 20u];                                          \
    }

#define PROC(V, Q0, Q1, LAB)                                              \
    {                                                                     \
        unsigned int row = (V) / 20u;          /* magic-mul div */        \
        int cbase  = (int)((V) - row * 20u) * 4;                          \
        int labrel = (LAB) - cbase;                                       \
        int sbase  = cbase * NBINS;                                       \
        float pe[8] = {Q0.x, Q0.y, Q0.z, Q0.w, Q1.x, Q1.y, Q1.z, Q1.w};   \
        unsigned int selq = 0u;                                           \
        _Pragma("unroll")                                                 \
        for (int j = 0; j < 8; ++j) {                                     \
            unsigned int q = (unsigned int)__builtin_fmaf(pe[j], QSF, 0.5f); \
            unsigned int t = min(q >> 8, 9u);                             \
            selq = (j == labrel) ? q : selq;                              \
            atomicAdd(&s_pack[sbase + j * NBINS + (int)t], q + (1u << 22)); \
        }                                                                 \
        if ((unsigned int)labrel < 8u) {                                  \
            unsigned int ts = min(selq >> 8, 9u);                         \
            atomicAdd(&s_acc[sbase + labrel * NBINS + (int)ts], 1u);      \
        }                                                                 \
    }

    {
        float4 a0, a1, b0, b1;
        int labA, labB;
        LOADS(v0, a0, a1, labA)
        for (;;) {
            unsigned int w1 = v0 + S;
            bool h1 = w1 < nvec;
            if (h1) LOADS(w1, b0, b1, labB)
            PROC(v0, a0, a1, labA)
            if (!h1) break;
            unsigned int w2 = w1 + S;
            bool h2 = w2 < nvec;
            if (h2) LOADS(w2, a0, a1, labA)
            PROC(w1, b0, b1, labB)
            if (!h2) break;
            v0 = w2;
        }
    }
#undef LOADS
#undef PROC

    __syncthreads();
    for (int i = threadIdx.x; i < NSLOTS; i += NTHR) {
        unsigned int pk = s_pack[i];
        unsigned int ac = s_acc[i];
        if (pk | ac) {
            unsigned long long sum = pk & 0x3FFFFFu;
            unsigned long long cnt = pk >> 22;
            atomicAdd(&g_pack[i], sum | (cnt << 36) | ((unsigned long long)ac << 53));
        }
    }
}

// ---------------------------------------------------------------------------
// Kernel 2: finalize in double precision. One block, 128 threads (80 active).
//   g_pack[slot]: sum_q (0..35, scale 2560) | cnt (36..52) | acc (53..63)
// ---------------------------------------------------------------------------
__global__ void __launch_bounds__(128)
mce_finalize(const unsigned long long* __restrict__ g_pack,
             float* __restrict__ out) {
    __shared__ double s_ce[128];
    int c = threadIdx.x;
    double ce = 0.0;
    if (c < NCLS) {
        double total = 0.0;
        for (int b = 0; b < NBINS; ++b)
            total += (double)((g_pack[c * NBINS + b] >> 36) & 0x1FFFFull);
        for (int b = 0; b < NBINS; ++b) {
            unsigned long long w = g_pack[c * NBINS + b];
            unsigned int n = (unsigned int)((w >> 36) & 0x1FFFFull);
            if (n > 0u) {
                double fn   = (double)n;
                double conf = ((double)(w & 0xFFFFFFFFFull) * (1.0 / 2560.0)) / fn;
                double acc  = (double)(w >> 53) / fn;
                double d    = conf - acc;
                ce += (fn / total) * d * d;
            }
        }
    }
    s_ce[c] = ce;
    __syncthreads();
    for (int off = 64; off > 0; off >>= 1) {
        if (c < off) s_ce[c] += s_ce[c + off];
        __syncthreads();
    }
    if (c == 0) out[0] = (float)sqrt(s_ce[0] / (double)NCLS);
}

extern "C" void kernel_launch(void* const* d_in, const int* in_sizes, int n_in,
                              void* d_out, int out_size, void* d_ws, size_t ws_size,
                              hipStream_t stream) {
    const float4* probas = (const float4*)d_in[0];
    const int*    labels = (const int*)d_in[1];

    unsigned int nvec = (unsigned int)(in_sizes[0] / 4);  // 20,000,000

    unsigned long long* g_pack = (unsigned long long*)d_ws;
    hipMemsetAsync(d_ws, 0, NSLOTS * sizeof(unsigned long long), stream);

    mce_accum<<<NBLK, NTHR, 0, stream>>>(probas, labels, g_pack, nvec);
    mce_finalize<<<1, 128, 0, stream>>>(g_pack, (float*)d_out);
}